// Round 5
// baseline (48.642 us; speedup 1.0000x reference)
//
#include <hip/hip_runtime.h>
#include <hip/hip_bf16.h>

// Segment-sum over ragged contiguous segments, single fused kernel.
// data: [TOTAL=1048576, D=64] fp32, lengths: [8192] int32 (sum == TOTAL)
// out:  [8192, 64] fp32
//
// One block = 8 waves (512 thr) = 8 consecutive segments. Each block
// redundantly computes prefix[8b] by block-reducing lengths[0..8b)
// (int4-vectorized, L2-resident). The block's own 8 lengths are cached in
// LDS; wave w adds its <w predecessors. Streaming loop: lane = rg*16 + c;
// thread sums float4 column-quad c over rows rg, rg+4, ...; 4-deep unroll.
// R5: non-temporal loads/stores via clang ext_vector f32x4 (HIP float4 is
// a class type the builtin rejects; f32x4 is layout-identical).

typedef float f32x4 __attribute__((ext_vector_type(4)));

__global__ __launch_bounds__(512) void seg_sum_fused(
    const float* __restrict__ data, const int* __restrict__ lengths,
    float* __restrict__ out, int n_seg) {
    const int tid = threadIdx.x;
    const int wave = tid >> 6;   // 0..7
    const int lane = tid & 63;
    const int s0 = blockIdx.x * 8;

    __shared__ int wsum[8];
    __shared__ int slen[8];

    if (tid < 8) {
        int idx = s0 + tid;
        slen[tid] = (idx < n_seg) ? lengths[idx] : 0;
    }

    // ---- block-wide sum of lengths[0..s0) ----
    const int n4 = s0 >> 2;  // s0 is a multiple of 8 -> multiple of 4
    const int4* __restrict__ l4 = reinterpret_cast<const int4*>(lengths);
    int psum = 0;
    for (int i = tid; i < n4; i += 512) {
        int4 v = l4[i];
        psum += v.x + v.y + v.z + v.w;
    }
    #pragma unroll
    for (int off = 32; off >= 1; off >>= 1) psum += __shfl_down(psum, off);
    if (lane == 0) wsum[wave] = psum;
    __syncthreads();

    int S = 0;
    #pragma unroll
    for (int j = 0; j < 8; ++j) S += wsum[j];  // prefix[s0]

    const int s = s0 + wave;
    if (s >= n_seg) return;

    int start = S;
    for (int j = 0; j < wave; ++j) start += slen[j];
    const int len = slen[wave];

    // ---- streaming sum ----
    const int c = lane & 15;   // f32x4 column quad (16 x f32x4 = 64 floats)
    const int rg = lane >> 4;  // row group 0..3

    const f32x4* __restrict__ p =
        reinterpret_cast<const f32x4*>(data) + (size_t)(start + rg) * 16 + c;

    f32x4 a0 = (f32x4)0.f;
    f32x4 a1 = (f32x4)0.f;
    f32x4 a2 = (f32x4)0.f;
    f32x4 a3 = (f32x4)0.f;

    int r = rg;
    for (; r + 12 < len; r += 16, p += 256) {
        f32x4 v0 = __builtin_nontemporal_load(p);
        f32x4 v1 = __builtin_nontemporal_load(p + 64);
        f32x4 v2 = __builtin_nontemporal_load(p + 128);
        f32x4 v3 = __builtin_nontemporal_load(p + 192);
        a0 += v0;
        a1 += v1;
        a2 += v2;
        a3 += v3;
    }
    for (; r < len; r += 4, p += 64) {
        a0 += __builtin_nontemporal_load(p);
    }
    a0 += a1 + a2 + a3;

    // Reduce across the 4 row groups (same c, lane stride 16).
    #pragma unroll
    for (int off = 32; off >= 16; off >>= 1) {
        a0.x += __shfl_down(a0.x, off);
        a0.y += __shfl_down(a0.y, off);
        a0.z += __shfl_down(a0.z, off);
        a0.w += __shfl_down(a0.w, off);
    }

    if (rg == 0) {
        __builtin_nontemporal_store(
            a0, reinterpret_cast<f32x4*>(out) + (size_t)s * 16 + c);
    }
}

extern "C" void kernel_launch(void* const* d_in, const int* in_sizes, int n_in,
                              void* d_out, int out_size, void* d_ws, size_t ws_size,
                              hipStream_t stream) {
    const float* data = (const float*)d_in[0];
    const int* lengths = (const int*)d_in[1];
    const int n_seg = in_sizes[1];
    float* out = (float*)d_out;

    const int grid = (n_seg + 7) / 8;  // 8 segments (waves) per block
    seg_sum_fused<<<grid, 512, 0, stream>>>(data, lengths, out, n_seg);
}

// Round 6
// 47.958 us; speedup vs baseline: 1.0143x; 1.0143x over previous
//
#include <hip/hip_runtime.h>
#include <hip/hip_bf16.h>

// Segment-sum over ragged contiguous segments, single fused kernel.
// data: [TOTAL=1048576, D=64] fp32, lengths: [8192] int32 (sum == TOTAL)
// out:  [8192, 64] fp32
//
// One block = 8 waves (512 thr) = 8 consecutive segments. Each block
// redundantly computes prefix[8b] by block-reducing lengths[0..8b)
// (int4-vectorized, L2-resident). The block's own 8 lengths are cached in
// LDS; wave w adds its <w predecessors. Streaming loop: lane = rg*16 + c;
// thread sums float4 column-quad c over rows rg, rg+4, ...; 4-deep unroll
// (4 independent accumulator chains, 4 loads in flight, base+imm offsets);
// shfl-reduce across the 4 row groups; lanes 0..15 store one float4 each.
//
// R6 = exact revert of R3 (best: 46.5 us, 5.55 TB/s effective).
// R5's non-temporal loads REGRESSED (48.6 us): no reuse to protect, and nt
// disables beneficial L2-side stream behavior on gfx950. Do not re-add.

__global__ __launch_bounds__(512) void seg_sum_fused(
    const float* __restrict__ data, const int* __restrict__ lengths,
    float* __restrict__ out, int n_seg) {
    const int tid = threadIdx.x;
    const int wave = tid >> 6;   // 0..7
    const int lane = tid & 63;
    const int s0 = blockIdx.x * 8;

    __shared__ int wsum[8];
    __shared__ int slen[8];

    if (tid < 8) {
        int idx = s0 + tid;
        slen[tid] = (idx < n_seg) ? lengths[idx] : 0;
    }

    // ---- block-wide sum of lengths[0..s0) ----
    const int n4 = s0 >> 2;  // s0 is a multiple of 8 -> multiple of 4
    const int4* __restrict__ l4 = reinterpret_cast<const int4*>(lengths);
    int psum = 0;
    for (int i = tid; i < n4; i += 512) {
        int4 v = l4[i];
        psum += v.x + v.y + v.z + v.w;
    }
    #pragma unroll
    for (int off = 32; off >= 1; off >>= 1) psum += __shfl_down(psum, off);
    if (lane == 0) wsum[wave] = psum;
    __syncthreads();

    int S = 0;
    #pragma unroll
    for (int j = 0; j < 8; ++j) S += wsum[j];  // prefix[s0]

    const int s = s0 + wave;
    if (s >= n_seg) return;

    int start = S;
    for (int j = 0; j < wave; ++j) start += slen[j];
    const int len = slen[wave];

    // ---- streaming sum ----
    const int c = lane & 15;   // float4 column quad (16 x float4 = 64 floats)
    const int rg = lane >> 4;  // row group 0..3

    const float4* __restrict__ p =
        reinterpret_cast<const float4*>(data) + (size_t)(start + rg) * 16 + c;

    float4 a0 = make_float4(0.f, 0.f, 0.f, 0.f);
    float4 a1 = make_float4(0.f, 0.f, 0.f, 0.f);
    float4 a2 = make_float4(0.f, 0.f, 0.f, 0.f);
    float4 a3 = make_float4(0.f, 0.f, 0.f, 0.f);

    int r = rg;
    for (; r + 12 < len; r += 16, p += 256) {
        float4 v0 = p[0];
        float4 v1 = p[64];
        float4 v2 = p[128];
        float4 v3 = p[192];
        a0.x += v0.x; a0.y += v0.y; a0.z += v0.z; a0.w += v0.w;
        a1.x += v1.x; a1.y += v1.y; a1.z += v1.z; a1.w += v1.w;
        a2.x += v2.x; a2.y += v2.y; a2.z += v2.z; a2.w += v2.w;
        a3.x += v3.x; a3.y += v3.y; a3.z += v3.z; a3.w += v3.w;
    }
    for (; r < len; r += 4, p += 64) {
        float4 v0 = p[0];
        a0.x += v0.x; a0.y += v0.y; a0.z += v0.z; a0.w += v0.w;
    }
    a0.x += a1.x + a2.x + a3.x;
    a0.y += a1.y + a2.y + a3.y;
    a0.z += a1.z + a2.z + a3.z;
    a0.w += a1.w + a2.w + a3.w;

    // Reduce across the 4 row groups (same c, lane stride 16).
    #pragma unroll
    for (int off = 32; off >= 16; off >>= 1) {
        a0.x += __shfl_down(a0.x, off);
        a0.y += __shfl_down(a0.y, off);
        a0.z += __shfl_down(a0.z, off);
        a0.w += __shfl_down(a0.w, off);
    }

    if (rg == 0) {
        reinterpret_cast<float4*>(out)[(size_t)s * 16 + c] = a0;
    }
}

extern "C" void kernel_launch(void* const* d_in, const int* in_sizes, int n_in,
                              void* d_out, int out_size, void* d_ws, size_t ws_size,
                              hipStream_t stream) {
    const float* data = (const float*)d_in[0];
    const int* lengths = (const int*)d_in[1];
    const int n_seg = in_sizes[1];
    float* out = (float*)d_out;

    const int grid = (n_seg + 7) / 8;  // 8 segments (waves) per block
    seg_sum_fused<<<grid, 512, 0, stream>>>(data, lengths, out, n_seg);
}